// Round 1
// 3470.718 us; speedup vs baseline: 1.2426x; 1.2426x over previous
//
#include <hip/hip_runtime.h>
#include <hip/hip_bf16.h>
#include <stdint.h>

typedef unsigned short u16;
typedef short short8 __attribute__((ext_vector_type(8)));
typedef float floatx4 __attribute__((ext_vector_type(4)));
typedef float f32x4 __attribute__((ext_vector_type(4)));

// ---------- numerics helpers ----------
__device__ __forceinline__ u16 f2bf(float f) {
  union { float f; uint32_t u; } v; v.f = f;
  return (u16)((v.u + 0x7FFFu + ((v.u >> 16) & 1u)) >> 16);
}
__device__ __forceinline__ float fexp(float x) {
  return __builtin_amdgcn_exp2f(x * 1.44269504088896340736f);
}
__device__ __forceinline__ float sigm(float x) {
  return __builtin_amdgcn_rcpf(1.0f + fexp(-x));
}
__device__ __forceinline__ float tanh_(float x) {
  return 1.0f - 2.0f * __builtin_amdgcn_rcpf(1.0f + fexp(2.0f * x));
}
// pack two f32 -> (bf16(hi)<<16)|bf16(lo), round-half-up via +0x8000 then byte-perm
__device__ __forceinline__ uint32_t packbf(float hi, float lo) {
  union { float f; uint32_t u; } a, b; a.f = hi; b.f = lo;
  return __builtin_amdgcn_perm(a.u + 0x8000u, b.u + 0x8000u, 0x07060302u);
}

// ---------- MALL-coherent access helpers (sc0 sc1 = bypass L1/L2, coherent
// at the Infinity-Cache coherence point; no buffer_wbl2 / buffer_inv needed) ----------
__device__ __forceinline__ short8 ld_b128_coh(const void* p) {
  short8 v;
  asm volatile("global_load_dwordx4 %0, %1, off sc0 sc1"
               : "=v"(v) : "v"(p) : "memory");
  return v;
}
__device__ __forceinline__ uint32_t ld_b32_coh_wait(const void* p) {
  uint32_t v;
  // waitcnt INSIDE the asm block: result is architecturally ready when the
  // asm "returns", so no sched_barrier is needed at the consumer (rule #18).
  asm volatile("global_load_dword %0, %1, off sc0 sc1\n\ts_waitcnt vmcnt(0)"
               : "=v"(v) : "v"(p) : "memory");
  return v;
}
__device__ __forceinline__ void st_b16_coh(void* p, uint32_t v) {
  asm volatile("global_store_short %0, %1, off sc0 sc1"
               :: "v"(p), "v"(v) : "memory");
}
__device__ __forceinline__ void st_b32_coh(void* p, uint32_t v) {
  asm volatile("global_store_dword %0, %1, off sc0 sc1"
               :: "v"(p), "v"(v) : "memory");
}

// ---------- K1: weight transpose + bf16 convert ----------
// Wi,Wh: [256][1024] fp32 (k-major). Wi_t/Wh_t: [1024][256] bf16 so MFMA
// B-fragments (8 consecutive k per lane) are contiguous 16B loads.
__global__ void k1_prep(const float* __restrict__ Wi, const float* __restrict__ Wh,
                        u16* __restrict__ Wi_t, u16* __restrict__ Wh_t) {
  const int idx = blockIdx.x * 256 + threadIdx.x;   // 0..262143
  const int n = idx >> 8, k = idx & 255;
  Wi_t[idx] = f2bf(Wi[k * 1024 + n]);
  Wh_t[idx] = f2bf(Wh[k * 1024 + n]);
}

// ---------- K3: fused scan, fence-free MALL message passing ----------
// 128 blocks x 64 threads. block = (g = blockIdx&7: 16 batch rows,
// j = blockIdx>>3: 16 h-cols -> 4 gate col sets). Wi and Wh slices register-
// resident.
//
// Cross-block protocol (NO fences, NO atomics, NO cache maintenance):
//  - all cross-block payload (h ring) + flags use sc0sc1 loads/stores, which
//    are coherent at the MALL. Producer: h stores (sc0sc1) -> s_waitcnt
//    vmcnt(0) (stores acked at coherence point) -> per-producer flag word
//    (sc0sc1). Consumer: poll 16 flag words (one 64B line, 16 lanes + __all)
//    -> h loads (sc0sc1, issued after poll in program order => see new data).
//  - flags: value t stored at flags[g][t&3][j] ("h(t) available"), depth-4
//    ring. ABA-safe: passing poll(t) requires all peers published flag(t),
//    i.e. all peers are at step >= t, so nobody reads slot t-3 anymore.
//    Exact-match compare (==t) makes stale values (t-4) harmless anyway.
//  - h ring depth 4: same proof as flags (all peers >= t when slot t-3 is
//    overwritten by h(t+1)).
// Removed vs previous version: buffer_wbl2 (release fence) and buffer_inv
// (acquire fence) full-L2 walks per step, and the 16-way serialized atomic
// RMW on a single flag address.
__global__ __launch_bounds__(64, 1) void k3_lstm(
    const u16* __restrict__ Wi_t, const u16* __restrict__ Wh_t,
    const float* __restrict__ x, const float* __restrict__ bh,
    u16* __restrict__ h_ring, uint32_t* __restrict__ flags,
    float* __restrict__ out) {
  const int g = blockIdx.x & 7;
  const int j = blockIdx.x >> 3;          // 0..15
  const int l = threadIdx.x;
  const int lq = l >> 4, ln = l & 15;
  const int colBase = j * 16 + ln;        // h-column 0..255

  // register-resident weight B-fragments: [gate][k-chunk]
  short8 bfI[4][8], bfW[4][8];
#pragma unroll
  for (int gp = 0; gp < 4; ++gp)
#pragma unroll
    for (int kk = 0; kk < 8; ++kk) {
      const size_t o = (size_t)(gp * 256 + colBase) * 256 + kk * 32 + lq * 8;
      bfI[gp][kk] = *(const short8*)(Wi_t + o);
      bfW[gp][kk] = *(const short8*)(Wh_t + o);
    }
  float bias[4];
#pragma unroll
  for (int gp = 0; gp < 4; ++gp) bias[gp] = bh[gp * 256 + colBase];

  // xga = xg(t) accumulator (bias + x_t @ Wi slice), in MFMA C layout
  floatx4 xga[4];
  {
    f32x4 xf[16];
    const float* xp = x + (size_t)(g * 16 + ln) * 262144 + lq * 8;  // t=0
#pragma unroll
    for (int kk = 0; kk < 8; ++kk) {
      xf[2 * kk]     = *(const f32x4*)(xp + kk * 32);
      xf[2 * kk + 1] = *(const f32x4*)(xp + kk * 32 + 4);
    }
#pragma unroll
    for (int gp = 0; gp < 4; ++gp)
      xga[gp] = (floatx4){bias[gp], bias[gp], bias[gp], bias[gp]};
#pragma unroll
    for (int kk = 0; kk < 8; ++kk) {
      union { uint32_t u[4]; short8 s; } cv;
      cv.u[0] = packbf(xf[2 * kk][1], xf[2 * kk][0]);
      cv.u[1] = packbf(xf[2 * kk][3], xf[2 * kk][2]);
      cv.u[2] = packbf(xf[2 * kk + 1][1], xf[2 * kk + 1][0]);
      cv.u[3] = packbf(xf[2 * kk + 1][3], xf[2 * kk + 1][2]);
#pragma unroll
      for (int gp = 0; gp < 4; ++gp)
        xga[gp] = __builtin_amdgcn_mfma_f32_16x16x32_bf16(cv.s, bfI[gp][kk],
                                                          xga[gp], 0, 0, 0);
    }
  }

  float creg[4] = {0.f, 0.f, 0.f, 0.f};
  float hv[4]   = {0.f, 0.f, 0.f, 0.f};

  for (int t = 0; t < 1024; ++t) {
    if (t > 0) {
      // poll 16 per-producer flag words (one 64B line); lanes 16..63 mirror
      const uint32_t* fp = flags + (((g << 2) | (t & 3)) << 4) + (l & 15);
      while (!__all(ld_b32_coh_wait(fp) == (uint32_t)t)) {}
    }
    // h(t) A-fragments from ring slot t&3 — coherent loads (fresh at MALL)
    const u16* hs = h_ring + (size_t)(t & 3) * 32768 + g * 4096;
    short8 af[8];
#pragma unroll
    for (int kk = 0; kk < 8; ++kk)
      af[kk] = ld_b128_coh(hs + ln * 256 + kk * 32 + lq * 8);
    asm volatile("s_waitcnt vmcnt(0)" ::: "memory");
    __builtin_amdgcn_sched_barrier(0);   // rule #18: pin MFMA after the wait
    // x(t+1) fp32 loads issued now: latency hidden under h-MFMA + publish
    f32x4 xf[16];
    if (t < 1023) {
      const float* xp = x + (size_t)(g * 16 + ln) * 262144 + (size_t)(t + 1) * 256 + lq * 8;
#pragma unroll
      for (int kk = 0; kk < 8; ++kk) {
        xf[2 * kk]     = *(const f32x4*)(xp + kk * 32);
        xf[2 * kk + 1] = *(const f32x4*)(xp + kk * 32 + 4);
      }
    }
    // gates = xga + h(t) @ Wh slice
    floatx4 acc[4];
#pragma unroll
    for (int gp = 0; gp < 4; ++gp) acc[gp] = xga[gp];
#pragma unroll
    for (int kk = 0; kk < 8; ++kk)
#pragma unroll
      for (int gp = 0; gp < 4; ++gp)
        acc[gp] = __builtin_amdgcn_mfma_f32_16x16x32_bf16(af[kk], bfW[gp][kk],
                                                          acc[gp], 0, 0, 0);
#pragma unroll
    for (int r = 0; r < 4; ++r) {
      const float iv = sigm(acc[0][r]);
      const float fv = sigm(acc[1][r]);
      const float gv = tanh_(acc[2][r]);
      const float ov = sigm(acc[3][r]);
      const float cc = fv * creg[r] + iv * gv;
      creg[r] = cc;
      hv[r] = ov * tanh_(cc);
    }
    // publish h(t+1) into slot (t+1)&3 — coherent stores, then drain, then flag
    u16* hd = h_ring + (size_t)((t + 1) & 3) * 32768 + g * 4096;
#pragma unroll
    for (int r = 0; r < 4; ++r)
      st_b16_coh(hd + (lq * 4 + r) * 256 + colBase, (uint32_t)f2bf(hv[r]));
    asm volatile("s_waitcnt vmcnt(0)" ::: "memory");  // h (+x) acked at MALL
    if (l == 0)
      st_b32_coh(flags + (((g << 2) | ((t + 1) & 3)) << 4) + j,
                 (uint32_t)(t + 1));
    // y(t) store (off critical path, drained by next step's poll waitcnt)
#pragma unroll
    for (int r = 0; r < 4; ++r)
      __builtin_nontemporal_store(
          hv[r], out + ((size_t)(g * 16 + lq * 4 + r) * 1024 + t) * 256 + colBase);
    // xg(t+1) = bias + x(t+1) @ Wi slice — in the peers' publish/poll shadow
    if (t < 1023) {
#pragma unroll
      for (int gp = 0; gp < 4; ++gp)
        xga[gp] = (floatx4){bias[gp], bias[gp], bias[gp], bias[gp]};
#pragma unroll
      for (int kk = 0; kk < 8; ++kk) {
        union { uint32_t u[4]; short8 s; } cv;
        cv.u[0] = packbf(xf[2 * kk][1], xf[2 * kk][0]);
        cv.u[1] = packbf(xf[2 * kk][3], xf[2 * kk][2]);
        cv.u[2] = packbf(xf[2 * kk + 1][1], xf[2 * kk + 1][0]);
        cv.u[3] = packbf(xf[2 * kk + 1][3], xf[2 * kk + 1][2]);
#pragma unroll
        for (int gp = 0; gp < 4; ++gp)
          xga[gp] = __builtin_amdgcn_mfma_f32_16x16x32_bf16(cv.s, bfI[gp][kk],
                                                            xga[gp], 0, 0, 0);
      }
    }
  }
  // finals: c_fin then h_fin after y
#pragma unroll
  for (int r = 0; r < 4; ++r) {
    const int b = g * 16 + lq * 4 + r;
    out[33554432 + b * 256 + colBase] = creg[r];
    out[33554432 + 32768 + b * 256 + colBase] = hv[r];
  }
}

// ---------- launch ----------
extern "C" void kernel_launch(void* const* d_in, const int* in_sizes, int n_in,
                              void* d_out, int out_size, void* d_ws, size_t ws_size,
                              hipStream_t stream) {
  const float* x  = (const float*)d_in[0];
  const float* Wi = (const float*)d_in[1];
  const float* Wh = (const float*)d_in[2];
  const float* bh = (const float*)d_in[3];
  char* ws = (char*)d_ws;
  // ws layout (~1.26 MB total):
  //   [0,       512K)   Wi_t bf16 [1024][256]
  //   [512K,    1M)     Wh_t bf16 [1024][256]
  //   [1M,      +2K)    flags u32 [8 g][4 slot][16 producer]
  //   [1M+4K,   +256K)  h ring bf16 [4][8][16][256]
  u16* Wi_t       = (u16*)(ws);
  u16* Wh_t       = (u16*)(ws + 524288);
  uint32_t* flags = (uint32_t*)(ws + 1048576);
  u16* h_ring     = (u16*)(ws + 1052672);
  float* out = (float*)d_out;

  hipMemsetAsync(flags, 0, 8 * 4 * 16 * 4, stream);
  hipMemsetAsync(h_ring, 0, 4 * 65536, stream);   // h(0)=0 (slot 0; all for hygiene)
  k1_prep<<<dim3(1024), dim3(256), 0, stream>>>(Wi, Wh, Wi_t, Wh_t);
  k3_lstm<<<dim3(128), dim3(64), 0, stream>>>(Wi_t, Wh_t, x, bh, h_ring, flags, out);
}

// Round 2
// 2603.427 us; speedup vs baseline: 1.6566x; 1.3331x over previous
//
#include <hip/hip_runtime.h>
#include <hip/hip_bf16.h>
#include <stdint.h>

typedef unsigned short u16;
typedef short short8 __attribute__((ext_vector_type(8)));
typedef float floatx4 __attribute__((ext_vector_type(4)));
typedef float f32x4 __attribute__((ext_vector_type(4)));

// ---------- numerics helpers ----------
__device__ __forceinline__ u16 f2bf(float f) {
  union { float f; uint32_t u; } v; v.f = f;
  return (u16)((v.u + 0x7FFFu + ((v.u >> 16) & 1u)) >> 16);
}
__device__ __forceinline__ float fexp(float x) {
  return __builtin_amdgcn_exp2f(x * 1.44269504088896340736f);
}
__device__ __forceinline__ float sigm(float x) {
  return __builtin_amdgcn_rcpf(1.0f + fexp(-x));
}
__device__ __forceinline__ float tanh_(float x) {
  return 1.0f - 2.0f * __builtin_amdgcn_rcpf(1.0f + fexp(2.0f * x));
}
// pack two f32 -> (bf16(hi)<<16)|bf16(lo), round-half-up via +0x8000 then byte-perm
__device__ __forceinline__ uint32_t packbf(float hi, float lo) {
  union { float f; uint32_t u; } a, b; a.f = hi; b.f = lo;
  return __builtin_amdgcn_perm(a.u + 0x8000u, b.u + 0x8000u, 0x07060302u);
}

// ---------- coherent access helpers ----------
// MALL scope (cross-XCD): sc0 sc1 — bypass L1+L2, coherent at Infinity Cache.
// XCD scope (same-L2):    sc0     — bypass (possibly stale) L1, hit shared L2.
// Producer release in XCD scope = plain write-through stores + s_waitcnt
// vmcnt(0) + plain flag store (LLVM's single-die agent-release lowering).
__device__ __forceinline__ short8 ld_b128_mall(const void* p) {
  short8 v;
  asm volatile("global_load_dwordx4 %0, %1, off sc0 sc1"
               : "=v"(v) : "v"(p) : "memory");
  return v;
}
__device__ __forceinline__ short8 ld_b128_xcd(const void* p) {
  short8 v;
  asm volatile("global_load_dwordx4 %0, %1, off sc0"
               : "=v"(v) : "v"(p) : "memory");
  return v;
}
__device__ __forceinline__ uint32_t ld_b32_mall_wait(const void* p) {
  uint32_t v;
  // waitcnt INSIDE the asm: value architecturally ready on "return".
  asm volatile("global_load_dword %0, %1, off sc0 sc1\n\ts_waitcnt vmcnt(0)"
               : "=v"(v) : "v"(p) : "memory");
  return v;
}
__device__ __forceinline__ uint32_t ld_b32_xcd_wait(const void* p) {
  uint32_t v;
  asm volatile("global_load_dword %0, %1, off sc0\n\ts_waitcnt vmcnt(0)"
               : "=v"(v) : "v"(p) : "memory");
  return v;
}
__device__ __forceinline__ void st_b16_mall(void* p, uint32_t v) {
  asm volatile("global_store_short %0, %1, off sc0 sc1"
               :: "v"(p), "v"(v) : "memory");
}
__device__ __forceinline__ void st_b32_mall(void* p, uint32_t v) {
  asm volatile("global_store_dword %0, %1, off sc0 sc1"
               :: "v"(p), "v"(v) : "memory");
}

// ---------- K1: weight transpose + bf16 convert ----------
__global__ void k1_prep(const float* __restrict__ Wi, const float* __restrict__ Wh,
                        u16* __restrict__ Wi_t, u16* __restrict__ Wh_t) {
  const int idx = blockIdx.x * 256 + threadIdx.x;   // 0..262143
  const int n = idx >> 8, k = idx & 255;
  Wi_t[idx] = f2bf(Wi[k * 1024 + n]);
  Wh_t[idx] = f2bf(Wh[k * 1024 + n]);
}

// ---------- scan body, templated on coherence scope ----------
// FAST (all 16 group members verified on one XCD): h ring + flags via shared
// per-XCD L2. Producer: plain WT stores -> vmcnt(0) -> plain flag store.
// Consumer: sc0 poll -> sc0 h loads (program order after resolved branch).
// SLOW: the proven MALL (sc0 sc1) protocol, unchanged semantics.
// Both: ring depth 4, flag value == t exact match (ABA-safe: flag(t) from all
// peers => all peers completed step t-1 => nobody still reads older slots).
template <bool FAST>
__device__ __forceinline__ void lstm_scan(
    const u16* __restrict__ Wi_t, const u16* __restrict__ Wh_t,
    const float* __restrict__ x, const float* __restrict__ bh,
    u16* __restrict__ h_ring, uint32_t* __restrict__ flags,
    float* __restrict__ out, int g, int j, int l) {
  const int lq = l >> 4, ln = l & 15;
  const int colBase = j * 16 + ln;        // h-column 0..255

  // register-resident weight B-fragments: [gate][k-chunk]
  short8 bfI[4][8], bfW[4][8];
#pragma unroll
  for (int gp = 0; gp < 4; ++gp)
#pragma unroll
    for (int kk = 0; kk < 8; ++kk) {
      const size_t o = (size_t)(gp * 256 + colBase) * 256 + kk * 32 + lq * 8;
      bfI[gp][kk] = *(const short8*)(Wi_t + o);
      bfW[gp][kk] = *(const short8*)(Wh_t + o);
    }
  float bias[4];
#pragma unroll
  for (int gp = 0; gp < 4; ++gp) bias[gp] = bh[gp * 256 + colBase];

  // xga = xg(0) = bias + x_0 @ Wi slice (MFMA C layout)
  floatx4 xga[4];
  {
    f32x4 xf[16];
    const float* xp = x + (size_t)(g * 16 + ln) * 262144 + lq * 8;
#pragma unroll
    for (int kk = 0; kk < 8; ++kk) {
      xf[2 * kk]     = *(const f32x4*)(xp + kk * 32);
      xf[2 * kk + 1] = *(const f32x4*)(xp + kk * 32 + 4);
    }
#pragma unroll
    for (int gp = 0; gp < 4; ++gp)
      xga[gp] = (floatx4){bias[gp], bias[gp], bias[gp], bias[gp]};
#pragma unroll
    for (int kk = 0; kk < 8; ++kk) {
      union { uint32_t u[4]; short8 s; } cv;
      cv.u[0] = packbf(xf[2 * kk][1], xf[2 * kk][0]);
      cv.u[1] = packbf(xf[2 * kk][3], xf[2 * kk][2]);
      cv.u[2] = packbf(xf[2 * kk + 1][1], xf[2 * kk + 1][0]);
      cv.u[3] = packbf(xf[2 * kk + 1][3], xf[2 * kk + 1][2]);
#pragma unroll
      for (int gp = 0; gp < 4; ++gp)
        xga[gp] = __builtin_amdgcn_mfma_f32_16x16x32_bf16(cv.s, bfI[gp][kk],
                                                          xga[gp], 0, 0, 0);
    }
  }

  float creg[4] = {0.f, 0.f, 0.f, 0.f};
  float hv[4]   = {0.f, 0.f, 0.f, 0.f};

  for (int t = 0; t < 1024; ++t) {
    if (t > 0) {
      // poll 16 per-producer flag words (one 64B line); lanes 16..63 mirror.
      // The in-asm vmcnt(0) also drains last step's y stores (plain/WT in
      // FAST => already retired; the first iteration pays any residual).
      const uint32_t* fp = flags + (((g << 2) | (t & 3)) << 4) + (l & 15);
      if (FAST) { while (!__all(ld_b32_xcd_wait(fp)  == (uint32_t)t)) {} }
      else      { while (!__all(ld_b32_mall_wait(fp) == (uint32_t)t)) {} }
    }
    // h(t) A-fragments first (8 loads), THEN x(t+1) loads (16). vmcnt retires
    // in issue order, so vmcnt(16) = "the 8 h loads are done, x still
    // flying" — x latency hides under MFMA+gates instead of the publish drain.
    const u16* hs = h_ring + (size_t)(t & 3) * 32768 + g * 4096;
    short8 af[8];
#pragma unroll
    for (int kk = 0; kk < 8; ++kk) {
      const u16* ap = hs + ln * 256 + kk * 32 + lq * 8;
      af[kk] = FAST ? ld_b128_xcd(ap) : ld_b128_mall(ap);
    }
    f32x4 xf[16];
    if (t < 1023) {
      const float* xp = x + (size_t)(g * 16 + ln) * 262144 + (size_t)(t + 1) * 256 + lq * 8;
#pragma unroll
      for (int kk = 0; kk < 8; ++kk) {
        xf[2 * kk]     = *(const f32x4*)(xp + kk * 32);
        xf[2 * kk + 1] = *(const f32x4*)(xp + kk * 32 + 4);
      }
      asm volatile("s_waitcnt vmcnt(16)" ::: "memory");   // h-frags ready
    } else {
      asm volatile("s_waitcnt vmcnt(0)" ::: "memory");
    }
    __builtin_amdgcn_sched_barrier(0);   // rule #18: pin MFMA after the wait
    // gates = xga + h(t) @ Wh slice
    floatx4 acc[4];
#pragma unroll
    for (int gp = 0; gp < 4; ++gp) acc[gp] = xga[gp];
#pragma unroll
    for (int kk = 0; kk < 8; ++kk)
#pragma unroll
      for (int gp = 0; gp < 4; ++gp)
        acc[gp] = __builtin_amdgcn_mfma_f32_16x16x32_bf16(af[kk], bfW[gp][kk],
                                                          acc[gp], 0, 0, 0);
#pragma unroll
    for (int r = 0; r < 4; ++r) {
      const float iv = sigm(acc[0][r]);
      const float fv = sigm(acc[1][r]);
      const float gv = tanh_(acc[2][r]);
      const float ov = sigm(acc[3][r]);
      const float cc = fv * creg[r] + iv * gv;
      creg[r] = cc;
      hv[r] = ov * tanh_(cc);
    }
    // publish h(t+1) into slot (t+1)&3: stores -> drain -> flag
    u16* hd = h_ring + (size_t)((t + 1) & 3) * 32768 + g * 4096;
#pragma unroll
    for (int r = 0; r < 4; ++r) {
      if (FAST) hd[(lq * 4 + r) * 256 + colBase] = f2bf(hv[r]);  // WT to L2
      else st_b16_mall(hd + (lq * 4 + r) * 256 + colBase, (uint32_t)f2bf(hv[r]));
    }
    asm volatile("s_waitcnt vmcnt(0)" ::: "memory");  // h acked at scope pt
    if (l == 0) {
      uint32_t* fp = flags + (((g << 2) | ((t + 1) & 3)) << 4) + j;
      if (FAST) *fp = (uint32_t)(t + 1);
      else st_b32_mall(fp, (uint32_t)(t + 1));
    }
    // y(t) store — plain WT in FAST (fast L2 ack, off next poll's drain)
#pragma unroll
    for (int r = 0; r < 4; ++r) {
      float* yp = out + ((size_t)(g * 16 + lq * 4 + r) * 1024 + t) * 256 + colBase;
      if (FAST) *yp = hv[r];
      else __builtin_nontemporal_store(hv[r], yp);
    }
    // xg(t+1) = bias + x(t+1) @ Wi slice — in the peers' publish/poll shadow
    if (t < 1023) {
#pragma unroll
      for (int gp = 0; gp < 4; ++gp)
        xga[gp] = (floatx4){bias[gp], bias[gp], bias[gp], bias[gp]};
#pragma unroll
      for (int kk = 0; kk < 8; ++kk) {
        union { uint32_t u[4]; short8 s; } cv;
        cv.u[0] = packbf(xf[2 * kk][1], xf[2 * kk][0]);
        cv.u[1] = packbf(xf[2 * kk][3], xf[2 * kk][2]);
        cv.u[2] = packbf(xf[2 * kk + 1][1], xf[2 * kk + 1][0]);
        cv.u[3] = packbf(xf[2 * kk + 1][3], xf[2 * kk + 1][2]);
#pragma unroll
        for (int gp = 0; gp < 4; ++gp)
          xga[gp] = __builtin_amdgcn_mfma_f32_16x16x32_bf16(cv.s, bfI[gp][kk],
                                                            xga[gp], 0, 0, 0);
      }
    }
  }
  // finals: c_fin then h_fin after y
#pragma unroll
  for (int r = 0; r < 4; ++r) {
    const int b = g * 16 + lq * 4 + r;
    out[33554432 + b * 256 + colBase] = creg[r];
    out[33554432 + 32768 + b * 256 + colBase] = hv[r];
  }
}

// ---------- K3: placement check + dispatch ----------
// Each block publishes its XCC_ID (MALL-coherent); each group member polls
// its 16 peers' IDs and computes fast = all-equal. Verdict is derived from
// identical data by every member => group-uniform. FAST rides the shared
// per-XCD L2; otherwise the proven MALL protocol. Correct for ANY placement.
__global__ __launch_bounds__(64, 1) void k3_lstm(
    const u16* __restrict__ Wi_t, const u16* __restrict__ Wh_t,
    const float* __restrict__ x, const float* __restrict__ bh,
    u16* __restrict__ h_ring, uint32_t* __restrict__ flags,
    uint32_t* __restrict__ xcc_arr, float* __restrict__ out) {
  const int g = blockIdx.x & 7;
  const int j = blockIdx.x >> 3;          // 0..15
  const int l = threadIdx.x;

  uint32_t xcc;
  asm volatile("s_getreg_b32 %0, hwreg(HW_REG_XCC_ID)" : "=s"(xcc));
  if (l == 0) st_b32_mall(xcc_arr + blockIdx.x, xcc + 1u);  // nonzero marker
  const uint32_t* xp_ = xcc_arr + g + 8 * (l & 15);         // my group's 16
  uint32_t peer;
  do { peer = ld_b32_mall_wait(xp_); } while (!__all(peer != 0u));
  const bool fast = (bool)__all(peer == __builtin_amdgcn_readfirstlane(peer));

  if (fast) lstm_scan<true >(Wi_t, Wh_t, x, bh, h_ring, flags, out, g, j, l);
  else      lstm_scan<false>(Wi_t, Wh_t, x, bh, h_ring, flags, out, g, j, l);
}

// ---------- launch ----------
extern "C" void kernel_launch(void* const* d_in, const int* in_sizes, int n_in,
                              void* d_out, int out_size, void* d_ws, size_t ws_size,
                              hipStream_t stream) {
  const float* x  = (const float*)d_in[0];
  const float* Wi = (const float*)d_in[1];
  const float* Wh = (const float*)d_in[2];
  const float* bh = (const float*)d_in[3];
  char* ws = (char*)d_ws;
  // ws layout (~1.26 MB total):
  //   [0,       512K)    Wi_t bf16 [1024][256]
  //   [512K,    1M)      Wh_t bf16 [1024][256]
  //   [1M,      +2K)     flags u32 [8 g][4 slot][16 producer]
  //   [1M+2K,   +512B)   xcc_arr u32 [128]
  //   [1M+4K,   +256K)   h ring bf16 [4][8][16][256]
  u16* Wi_t         = (u16*)(ws);
  u16* Wh_t         = (u16*)(ws + 524288);
  uint32_t* flags   = (uint32_t*)(ws + 1048576);
  uint32_t* xcc_arr = (uint32_t*)(ws + 1048576 + 2048);
  u16* h_ring       = (u16*)(ws + 1052672);
  float* out = (float*)d_out;

  hipMemsetAsync(ws + 1048576, 0, 4096, stream);  // flags + xcc_arr
  hipMemsetAsync(h_ring, 0, 4 * 65536, stream);   // h(0)=0 (slot 0; all for hygiene)
  k1_prep<<<dim3(1024), dim3(256), 0, stream>>>(Wi, Wh, Wi_t, Wh_t);
  k3_lstm<<<dim3(128), dim3(64), 0, stream>>>(Wi_t, Wh_t, x, bh, h_ring, flags,
                                              xcc_arr, out);
}

// Round 4
// 2602.450 us; speedup vs baseline: 1.6572x; 1.0004x over previous
//
#include <hip/hip_runtime.h>
#include <hip/hip_bf16.h>
#include <stdint.h>

typedef unsigned short u16;
typedef short short8 __attribute__((ext_vector_type(8)));
typedef float floatx4 __attribute__((ext_vector_type(4)));
typedef float f32x4 __attribute__((ext_vector_type(4)));

// ---------- numerics helpers ----------
__device__ __forceinline__ u16 f2bf(float f) {
  union { float f; uint32_t u; } v; v.f = f;
  return (u16)((v.u + 0x7FFFu + ((v.u >> 16) & 1u)) >> 16);
}
__device__ __forceinline__ float fexp(float x) {
  return __builtin_amdgcn_exp2f(x * 1.44269504088896340736f);
}
__device__ __forceinline__ float sigm(float x) {
  return __builtin_amdgcn_rcpf(1.0f + fexp(-x));
}
__device__ __forceinline__ float tanh_(float x) {
  return 1.0f - 2.0f * __builtin_amdgcn_rcpf(1.0f + fexp(2.0f * x));
}
__device__ __forceinline__ uint32_t packbf(float hi, float lo) {
  union { float f; uint32_t u; } a, b; a.f = hi; b.f = lo;
  return __builtin_amdgcn_perm(a.u + 0x8000u, b.u + 0x8000u, 0x07060302u);
}

// ---------- coherent access helpers ----------
// MALL scope (cross-XCD): sc0 sc1 — coherent at Infinity Cache.
// XCD scope (same-L2):    sc0     — bypass possibly-stale L1, hit shared L2.
__device__ __forceinline__ short8 ld_b128_mall(const void* p) {
  short8 v;
  asm volatile("global_load_dwordx4 %0, %1, off sc0 sc1"
               : "=v"(v) : "v"(p) : "memory");
  return v;
}
__device__ __forceinline__ short8 ld_b128_xcd(const void* p) {
  short8 v;
  asm volatile("global_load_dwordx4 %0, %1, off sc0"
               : "=v"(v) : "v"(p) : "memory");
  return v;
}
__device__ __forceinline__ uint32_t ld_b32_mall_wait(const void* p) {
  uint32_t v;
  asm volatile("global_load_dword %0, %1, off sc0 sc1\n\ts_waitcnt vmcnt(0)"
               : "=v"(v) : "v"(p) : "memory");
  return v;
}
__device__ __forceinline__ uint32_t ld_b32_xcd_wait(const void* p) {
  uint32_t v;
  asm volatile("global_load_dword %0, %1, off sc0\n\ts_waitcnt vmcnt(0)"
               : "=v"(v) : "v"(p) : "memory");
  return v;
}
__device__ __forceinline__ void st_b16_mall(void* p, uint32_t v) {
  asm volatile("global_store_short %0, %1, off sc0 sc1"
               :: "v"(p), "v"(v) : "memory");
}
__device__ __forceinline__ void st_b32_mall(void* p, uint32_t v) {
  asm volatile("global_store_dword %0, %1, off sc0 sc1"
               :: "v"(p), "v"(v) : "memory");
}

// ---------- K1: weight transpose + bf16 convert ----------
__global__ void k1_prep(const float* __restrict__ Wi, const float* __restrict__ Wh,
                        u16* __restrict__ Wi_t, u16* __restrict__ Wh_t) {
  const int idx = blockIdx.x * 256 + threadIdx.x;   // 0..262143
  const int n = idx >> 8, k = idx & 255;
  Wi_t[idx] = f2bf(Wi[k * 1024 + n]);
  Wh_t[idx] = f2bf(Wh[k * 1024 + n]);
}

// ---------- scan body (single wave, R2-proven protocol, reordered) ----------
// Step order is chosen so that AT THE PUBLISH DRAIN the only in-flight vmem
// ops are the 4 h-stores (vmcnt retires in issue order — any older HBM x
// load would stall the flag). x(t+2) loads are issued AFTER the flag and
// drained by the NEXT step's poll vmcnt(0), i.e. their ~900cy HBM latency
// lands in the flag-wait slack instead of on the handshake path.
// Cross-block protocol identical to R2 (proven): FAST = per-XCD L2 (sc0
// loads, plain WT stores, vmcnt(0) release), SLOW = MALL (sc0 sc1).
// Flags: value t at flags[g][t&3][producer], one 64B line per producer.
// Ring depth 4, exact-match poll (ABA-safe: skew between blocks <= 1 step).
template <bool FAST>
__device__ __forceinline__ void lstm_scan(
    const u16* __restrict__ Wi_t, const u16* __restrict__ Wh_t,
    const float* __restrict__ x, const float* __restrict__ bh,
    u16* __restrict__ h_ring, uint32_t* __restrict__ flags,
    float* __restrict__ out, int g, int j, int l) {
  const int lq = l >> 4, ln = l & 15;
  const int colBase = j * 16 + ln;        // h-column 0..255

  // register-resident weight B-fragments: [gate][k-chunk] (compiler -> AGPR)
  short8 bfI[4][8], bfW[4][8];
#pragma unroll
  for (int gp = 0; gp < 4; ++gp)
#pragma unroll
    for (int kk = 0; kk < 8; ++kk) {
      const size_t o = (size_t)(gp * 256 + colBase) * 256 + kk * 32 + lq * 8;
      bfI[gp][kk] = *(const short8*)(Wi_t + o);
      bfW[gp][kk] = *(const short8*)(Wh_t + o);
    }
  float bias[4];
#pragma unroll
  for (int gp = 0; gp < 4; ++gp) bias[gp] = bh[gp * 256 + colBase];

  const float* xrow = x + (size_t)(g * 16 + ln) * 262144 + lq * 8;
  union CV { uint32_t u[4]; short8 s; };

  // prologue: load+pack x(0), xga(0) = bias + x(0)@Wi, then issue x(1)
  f32x4 xf[16];
  CV cv[8];
  floatx4 xga[4];
#pragma unroll
  for (int kk = 0; kk < 8; ++kk) {
    xf[2 * kk]     = *(const f32x4*)(xrow + kk * 32);
    xf[2 * kk + 1] = *(const f32x4*)(xrow + kk * 32 + 4);
  }
#pragma unroll
  for (int kk = 0; kk < 8; ++kk) {
    cv[kk].u[0] = packbf(xf[2 * kk][1], xf[2 * kk][0]);
    cv[kk].u[1] = packbf(xf[2 * kk][3], xf[2 * kk][2]);
    cv[kk].u[2] = packbf(xf[2 * kk + 1][1], xf[2 * kk + 1][0]);
    cv[kk].u[3] = packbf(xf[2 * kk + 1][3], xf[2 * kk + 1][2]);
  }
#pragma unroll
  for (int gp = 0; gp < 4; ++gp)
    xga[gp] = (floatx4){bias[gp], bias[gp], bias[gp], bias[gp]};
#pragma unroll
  for (int kk = 0; kk < 8; ++kk)
#pragma unroll
    for (int gp = 0; gp < 4; ++gp)
      xga[gp] = __builtin_amdgcn_mfma_f32_16x16x32_bf16(cv[kk].s, bfI[gp][kk],
                                                        xga[gp], 0, 0, 0);
  // issue x(1) — consumed at end of step 0, drained at step 0's first vmcnt
#pragma unroll
  for (int kk = 0; kk < 8; ++kk) {
    xf[2 * kk]     = *(const f32x4*)(xrow + 256 + kk * 32);
    xf[2 * kk + 1] = *(const f32x4*)(xrow + 256 + kk * 32 + 4);
  }

  float creg[4] = {0.f, 0.f, 0.f, 0.f};
  float hv[4]   = {0.f, 0.f, 0.f, 0.f};

  for (int t = 0; t < 1024; ++t) {
    // 1. poll flag(t): in-asm vmcnt(0) also drains y(t-1) stores and the
    //    x(t+1) loads issued at the end of step t-1 (latency in flag slack)
    if (t > 0) {
      const uint32_t* fp = flags + (((g << 2) | (t & 3)) << 8) + ((l & 15) << 4);
      if (FAST) { while (!__all(ld_b32_xcd_wait(fp)  == (uint32_t)t)) {} }
      else      { while (!__all(ld_b32_mall_wait(fp) == (uint32_t)t)) {} }
    }
    // 2. h(t) A-fragments from ring slot t&3 (only vmem now in flight)
    const u16* hs = h_ring + (size_t)(t & 3) * 32768 + g * 4096;
    short8 af[8];
#pragma unroll
    for (int kk = 0; kk < 8; ++kk) {
      const u16* ap = hs + ln * 256 + kk * 32 + lq * 8;
      af[kk] = FAST ? ld_b128_xcd(ap) : ld_b128_mall(ap);
    }
    asm volatile("s_waitcnt vmcnt(0)" ::: "memory");
    __builtin_amdgcn_sched_barrier(0);   // rule #18: pin MFMA after the wait
    // 3. gates = xga(t) + h(t) @ Wh slice
    floatx4 acc[4];
#pragma unroll
    for (int gp = 0; gp < 4; ++gp) acc[gp] = xga[gp];
#pragma unroll
    for (int kk = 0; kk < 8; ++kk)
#pragma unroll
      for (int gp = 0; gp < 4; ++gp)
        acc[gp] = __builtin_amdgcn_mfma_f32_16x16x32_bf16(af[kk], bfW[gp][kk],
                                                          acc[gp], 0, 0, 0);
#pragma unroll
    for (int r = 0; r < 4; ++r) {
      const float iv = sigm(acc[0][r]);
      const float fv = sigm(acc[1][r]);
      const float gv = tanh_(acc[2][r]);
      const float ov = sigm(acc[3][r]);
      const float cc = fv * creg[r] + iv * gv;
      creg[r] = cc;
      hv[r] = ov * tanh_(cc);
    }
    // 4. publish h(t+1): stores -> drain (ONLY these 4 stores fly) -> flag
    u16* hd = h_ring + (size_t)((t + 1) & 3) * 32768 + g * 4096;
#pragma unroll
    for (int r = 0; r < 4; ++r) {
      if (FAST) hd[(lq * 4 + r) * 256 + colBase] = f2bf(hv[r]);
      else st_b16_mall(hd + (lq * 4 + r) * 256 + colBase, (uint32_t)f2bf(hv[r]));
    }
    asm volatile("s_waitcnt vmcnt(0)" ::: "memory");
    if (l == 0) {
      uint32_t* fp = flags + (((g << 2) | ((t + 1) & 3)) << 8) + (j << 4);
      if (FAST) *fp = (uint32_t)(t + 1);
      else st_b32_mall(fp, (uint32_t)(t + 1));
    }
    // 5. y(t) store — after the flag, drained by next step's poll
#pragma unroll
    for (int r = 0; r < 4; ++r) {
      float* yp = out + ((size_t)(g * 16 + lq * 4 + r) * 1024 + t) * 256 + colBase;
      if (FAST) *yp = hv[r];
      else __builtin_nontemporal_store(hv[r], yp);
    }
    // 6. pack x(t+1) -> bf16 (frees xf), issue x(t+2), compute xg(t+1)
    if (t < 1023) {
#pragma unroll
      for (int kk = 0; kk < 8; ++kk) {
        cv[kk].u[0] = packbf(xf[2 * kk][1], xf[2 * kk][0]);
        cv[kk].u[1] = packbf(xf[2 * kk][3], xf[2 * kk][2]);
        cv[kk].u[2] = packbf(xf[2 * kk + 1][1], xf[2 * kk + 1][0]);
        cv[kk].u[3] = packbf(xf[2 * kk + 1][3], xf[2 * kk + 1][2]);
      }
      if (t < 1022) {
        const float* xp = xrow + (size_t)(t + 2) * 256;
#pragma unroll
        for (int kk = 0; kk < 8; ++kk) {
          xf[2 * kk]     = *(const f32x4*)(xp + kk * 32);
          xf[2 * kk + 1] = *(const f32x4*)(xp + kk * 32 + 4);
        }
      }
#pragma unroll
      for (int gp = 0; gp < 4; ++gp)
        xga[gp] = (floatx4){bias[gp], bias[gp], bias[gp], bias[gp]};
#pragma unroll
      for (int kk = 0; kk < 8; ++kk)
#pragma unroll
        for (int gp = 0; gp < 4; ++gp)
          xga[gp] = __builtin_amdgcn_mfma_f32_16x16x32_bf16(cv[kk].s, bfI[gp][kk],
                                                            xga[gp], 0, 0, 0);
    }
  }
  // finals: c_fin then h_fin after y
#pragma unroll
  for (int r = 0; r < 4; ++r) {
    const int b = g * 16 + lq * 4 + r;
    out[33554432 + b * 256 + colBase] = creg[r];
    out[33554432 + 32768 + b * 256 + colBase] = hv[r];
  }
}

// ---------- K3: placement check + dispatch (R2-proven) ----------
__global__ __launch_bounds__(64, 1) void k3_lstm(
    const u16* __restrict__ Wi_t, const u16* __restrict__ Wh_t,
    const float* __restrict__ x, const float* __restrict__ bh,
    u16* __restrict__ h_ring, uint32_t* __restrict__ flags,
    uint32_t* __restrict__ xcc_arr, float* __restrict__ out) {
  const int g = blockIdx.x & 7;
  const int j = blockIdx.x >> 3;          // 0..15
  const int l = threadIdx.x;

  uint32_t xcc;
  asm volatile("s_getreg_b32 %0, hwreg(HW_REG_XCC_ID)" : "=s"(xcc));
  if (l == 0) st_b32_mall(xcc_arr + blockIdx.x, xcc + 1u);  // nonzero marker
  const uint32_t* xp_ = xcc_arr + g + 8 * (l & 15);         // my group's 16
  uint32_t peer;
  do { peer = ld_b32_mall_wait(xp_); } while (!__all(peer != 0u));
  const bool fast = (bool)__all(peer == __builtin_amdgcn_readfirstlane(peer));

  if (fast) lstm_scan<true >(Wi_t, Wh_t, x, bh, h_ring, flags, out, g, j, l);
  else      lstm_scan<false>(Wi_t, Wh_t, x, bh, h_ring, flags, out, g, j, l);
}

// ---------- launch ----------
extern "C" void kernel_launch(void* const* d_in, const int* in_sizes, int n_in,
                              void* d_out, int out_size, void* d_ws, size_t ws_size,
                              hipStream_t stream) {
  const float* x  = (const float*)d_in[0];
  const float* Wi = (const float*)d_in[1];
  const float* Wh = (const float*)d_in[2];
  const float* bh = (const float*)d_in[3];
  char* ws = (char*)d_ws;
  // ws layout (~1.29 MB total):
  //   [0,        512K)   Wi_t bf16 [1024][256]
  //   [512K,     1M)     Wh_t bf16 [1024][256]
  //   [1M,       +32K)   flags u32 [8 g][4 slot][16 producer][16 pad] (64B/line)
  //   [1M+32K,   +512B)  xcc_arr u32 [128]
  //   [1M+36K,   +256K)  h ring bf16 [4][8][16][256]
  u16* Wi_t         = (u16*)(ws);
  u16* Wh_t         = (u16*)(ws + 524288);
  uint32_t* flags   = (uint32_t*)(ws + 1048576);
  uint32_t* xcc_arr = (uint32_t*)(ws + 1048576 + 32768);
  u16* h_ring       = (u16*)(ws + 1048576 + 36864);
  float* out = (float*)d_out;

  hipMemsetAsync(ws + 1048576, 0, 36864, stream);  // flags + xcc_arr
  hipMemsetAsync(h_ring, 0, 4 * 65536, stream);    // h(0)=0
  k1_prep<<<dim3(1024), dim3(256), 0, stream>>>(Wi, Wh, Wi_t, Wh_t);
  k3_lstm<<<dim3(128), dim3(64), 0, stream>>>(Wi_t, Wh_t, x, bh, h_ring, flags,
                                              xcc_arr, out);
}